// Round 6
// baseline (220.098 us; speedup 1.0000x reference)
//
#include <hip/hip_runtime.h>

typedef unsigned short u16;
typedef unsigned int u32;
typedef short bf16x8s __attribute__((ext_vector_type(8)));
typedef float f32x4 __attribute__((ext_vector_type(4)));

#define SCALE_C 0.044194173824159216f  // 512^-0.5
#define MFMA16 __builtin_amdgcn_mfma_f32_16x16x32_bf16

__device__ __forceinline__ u16 f2bf(float f){
  union { float f; u32 u; } c; c.f = f;
  u32 u = c.u;
  return (u16)((u + 0x7fffu + ((u >> 16) & 1u)) >> 16);
}

__device__ __forceinline__ void gload16(const void* g, void* l){
  __builtin_amdgcn_global_load_lds((const __attribute__((address_space(1))) void*)g,
                                   (__attribute__((address_space(3))) void*)l, 16, 0, 0);
}

// ---------------- workspace layout (bytes) ----------------
#define OFF_KXB  ((size_t)0)                  // 32768*512*2
#define OFF_G    (OFF_KXB + 33554432)         // 256*128*128*2
#define OFF_W2B  (OFF_G + 8388608)            // 1000*2048*2
#define OFF_H    (OFF_W2B + 4096000)          // 512*2048*2
#define OFF_W1B  (OFF_H + 2097152)            // 2048*512*2
#define OFF_QLN  (OFF_W1B + 2097152)          // 512*512*2 each below
#define OFF_QHAT (OFF_QLN + 524288)
#define OFF_QXB  (OFF_QHAT + 524288)
#define OFF_P    (OFF_QXB + 524288)
#define OFF_M2   (OFF_P + 524288)
#define OFF_WQB  (OFF_M2 + 524288)
#define OFF_WKT  (OFF_WQB + 524288)
#define OFF_KM   (OFF_WKT + 524288)           // 32768*4
#define OFF_KR   (OFF_KM + 131072)
#define OFF_T2   (OFF_KR + 131072)            // 512*4
#define OFF_FLAG (OFF_T2 + 4096)

// ======== GRAM+PREPK fused (512 thr): reads f32 kx, emits kxb/km/kr/G ======
__global__ __launch_bounds__(512) void k_gram_fused(
    const float* __restrict__ kx, u16* __restrict__ kxb,
    float* __restrict__ km, float* __restrict__ kr, u16* __restrict__ Gm)
{
  __shared__ __align__(16) u16 lk[128*512];   // 128 KB, swizzled per 64-col chunk
  const int z = blockIdx.x, tid = threadIdx.x;
  const int lane = tid & 63, w = tid >> 6;    // 8 waves
  // convert + stats: wave w owns rows [w*16, w*16+16)
  for (int i = 0; i < 16; i++){
    const int r = w*16 + i;
    const float* x = kx + ((size_t)z*128 + r)*512;
    float4 a = *(const float4*)(x + lane*8);
    float4 b = *(const float4*)(x + lane*8 + 4);
    float s  = a.x+a.y+a.z+a.w + b.x+b.y+b.z+b.w;
    float sq = a.x*a.x+a.y*a.y+a.z*a.z+a.w*a.w + b.x*b.x+b.y*b.y+b.z*b.z+b.w*b.w;
    #pragma unroll
    for (int o = 1; o < 64; o <<= 1){ s += __shfl_xor(s,o); sq += __shfl_xor(sq,o); }
    float mean = s*(1.0f/512.0f);
    float var  = sq*(1.0f/512.0f) - mean*mean;
    float rstd = rsqrtf(var + 1e-5f);
    uint4 p;
    p.x = f2bf(a.x)|((u32)f2bf(a.y)<<16); p.y = f2bf(a.z)|((u32)f2bf(a.w)<<16);
    p.z = f2bf(b.x)|((u32)f2bf(b.y)<<16); p.w = f2bf(b.z)|((u32)f2bf(b.w)<<16);
    *(uint4*)(kxb + ((size_t)z*128 + r)*512 + lane*8) = p;
    *(uint4*)&lk[r*512 + (lane>>3)*64 + (((lane&7)^(r&7))*8)] = p;
    if (lane == 0){ km[z*128+r] = mean; kr[z*128+r] = rstd; }
  }
  __syncthreads();
  // G = X X^T from LDS; 8 waves = 2x4 grid of [64,32] output tiles
  const int a0 = (w>>2)*64, b0 = (w&3)*32;
  const int l15 = lane & 15, lg = lane >> 4;
  f32x4 acc[4][2] = {};
  #pragma unroll
  for (int ch = 0; ch < 8; ch++){
    #pragma unroll
    for (int kk = 0; kk < 2; kk++){
      int cgr = kk*4 + lg;
      bf16x8s a[4], b[2];
      #pragma unroll
      for (int i = 0; i < 4; i++){
        int r = a0 + i*16 + l15;
        a[i] = *(const bf16x8s*)&lk[r*512 + ch*64 + ((cgr^(r&7))*8)];
      }
      #pragma unroll
      for (int j = 0; j < 2; j++){
        int r = b0 + j*16 + l15;
        b[j] = *(const bf16x8s*)&lk[r*512 + ch*64 + ((cgr^(r&7))*8)];
      }
      #pragma unroll
      for (int i = 0; i < 4; i++)
        #pragma unroll
        for (int j = 0; j < 2; j++)
          acc[i][j] = MFMA16(a[i], b[j], acc[i][j], 0,0,0);
    }
  }
  u16* G = Gm + (size_t)z*16384;
  #pragma unroll
  for (int i = 0; i < 4; i++)
    #pragma unroll
    for (int j = 0; j < 2; j++)
      #pragma unroll
      for (int r = 0; r < 4; r++)
        G[(size_t)(a0 + i*16 + lg*4 + r)*128 + b0 + j*16 + l15] = f2bf(acc[i][j][r]);
}

// ===================== PHASE A (light): q-prep, weights, mask ==============
__global__ __launch_bounds__(256) void k_phaseA(
    const float* __restrict__ qx, const int* __restrict__ maskw,
    const float* __restrict__ g_q, const float* __restrict__ b_q,
    const float* __restrict__ wq, const float* __restrict__ wk,
    const float* __restrict__ w1, const float* __restrict__ w2,
    u16* __restrict__ qln, u16* __restrict__ qhat, u16* __restrict__ qxb,
    u16* __restrict__ wqb, u16* __restrict__ wkt, u16* __restrict__ w1b,
    u16* __restrict__ w2b, float* __restrict__ t2s, int* __restrict__ flag)
{
  const int bid = blockIdx.x, tid = threadIdx.x;
  if (bid < 512){
    __shared__ float redq[4][2];
    const int row = bid;
    const int lane = tid & 63, wv = tid >> 6;
    float2 v = *(const float2*)(qx + (size_t)row*512 + tid*2);
    float s = v.x+v.y, sq = v.x*v.x+v.y*v.y;
    #pragma unroll
    for (int o = 1; o < 64; o <<= 1){ s += __shfl_xor(s,o); sq += __shfl_xor(sq,o); }
    if (lane == 0){ redq[wv][0]=s; redq[wv][1]=sq; }
    __syncthreads();
    s  = redq[0][0]+redq[1][0]+redq[2][0]+redq[3][0];
    sq = redq[0][1]+redq[1][1]+redq[2][1]+redq[3][1];
    float mean = s*(1.0f/512.0f);
    float var  = sq*(1.0f/512.0f) - mean*mean;
    float rstd = rsqrtf(var + 1e-5f);
    float il2  = 1.0f / fmaxf(sqrtf(sq), 1e-12f);
    float2 g  = *(const float2*)(g_q + tid*2);
    float2 bb = *(const float2*)(b_q + tid*2);
    u32 a  = f2bf((v.x-mean)*rstd*g.x+bb.x) | ((u32)f2bf((v.y-mean)*rstd*g.y+bb.y)<<16);
    u32 h  = f2bf(v.x*il2) | ((u32)f2bf(v.y*il2)<<16);
    u32 xx = f2bf(v.x)     | ((u32)f2bf(v.y)<<16);
    *(u32*)(qln  + (size_t)row*512 + tid*2) = a;
    *(u32*)(qhat + (size_t)row*512 + tid*2) = h;
    *(u32*)(qxb  + (size_t)row*512 + tid*2) = xx;
  } else if (bid < 3792){
    const float* in; u16* out; int i;
    if (bid < 768)       { in = wq; out = wqb; i = (bid-512)*256 + tid; }
    else if (bid < 1792) { in = w1; out = w1b; i = (bid-768)*256 + tid; }
    else                 { in = w2; out = w2b; i = (bid-1792)*256 + tid; }
    float4 v = *(const float4*)(in + (size_t)i*4);
    uint2 p;
    p.x = f2bf(v.x)|((u32)f2bf(v.y)<<16); p.y = f2bf(v.z)|((u32)f2bf(v.w)<<16);
    *(uint2*)(out + (size_t)i*4) = p;
  } else if (bid < 4048){
    __shared__ float tile[32][33];
    const int t = bid - 3792;
    const int bx = (t & 15)*32, by = (t >> 4)*32;
    const int tx = tid & 31, ty = tid >> 5;
    #pragma unroll
    for (int r = 0; r < 32; r += 8) tile[ty+r][tx] = wk[(size_t)(by+ty+r)*512 + bx+tx];
    __syncthreads();
    #pragma unroll
    for (int r = 0; r < 32; r += 8) wkt[(size_t)(bx+ty+r)*512 + by+tx] = f2bf(tile[tx][ty+r]);
  } else {
    __shared__ int smax;
    if (tid == 0) smax = 0;
    t2s[tid] = 0.0f; t2s[tid+256] = 0.0f;
    __syncthreads();
    int mx = 0;
    for (int i = tid; i < 8192; i += 256){ int v = maskw[i]; mx = v > mx ? v : mx; }
    #pragma unroll
    for (int o = 1; o < 64; o <<= 1){ int t2 = __shfl_xor(mx,o); mx = t2 > mx ? t2 : mx; }
    if ((tid & 63) == 0) atomicMax(&smax, mx);
    __syncthreads();
    if (tid == 0) *flag = (smax <= 1) ? 1 : 0;
  }
}

// ------------- 64x64 GEMM body (round-1/2 proven, register-staged) ---------
__device__ __forceinline__ void gemm_body(const u16* __restrict__ Ap, const u16* __restrict__ Bp,
    int M, int N, int K, int m0, int n0, int tid,
    u16 (*lA)[64], u16 (*lB)[64], f32x4 (&acc)[2][2])
{
  const int lane = tid & 63, w = tid >> 6;
  const int wr = (w >> 1)*32, wc = (w & 1)*32;
  const int l15 = lane & 15, lg = lane >> 4;
  for (int kc = 0; kc < K; kc += 64){
    #pragma unroll
    for (int s = 0; s < 2; s++){
      int u = tid + s*256;
      int row = u >> 3, cg = u & 7;
      int sw = (cg ^ (row & 7)) * 8;
      uint4 va = make_uint4(0,0,0,0);
      if (m0 + row < M) va = *(const uint4*)(Ap + (size_t)(m0+row)*K + kc + cg*8);
      *(uint4*)&lA[row][sw] = va;
      uint4 vb = make_uint4(0,0,0,0);
      if (n0 + row < N) vb = *(const uint4*)(Bp + (size_t)(n0+row)*K + kc + cg*8);
      *(uint4*)&lB[row][sw] = vb;
    }
    __syncthreads();
    #pragma unroll
    for (int kk = 0; kk < 2; kk++){
      int cgr = kk*4 + lg;
      int ra0 = wr + l15, ra1 = wr + 16 + l15;
      int rb0 = wc + l15, rb1 = wc + 16 + l15;
      bf16x8s a0 = *(const bf16x8s*)&lA[ra0][(cgr ^ (ra0&7))*8];
      bf16x8s a1 = *(const bf16x8s*)&lA[ra1][(cgr ^ (ra1&7))*8];
      bf16x8s b0 = *(const bf16x8s*)&lB[rb0][(cgr ^ (rb0&7))*8];
      bf16x8s b1 = *(const bf16x8s*)&lB[rb1][(cgr ^ (rb1&7))*8];
      acc[0][0] = MFMA16(a0,b0,acc[0][0],0,0,0);
      acc[0][1] = MFMA16(a0,b1,acc[0][1],0,0,0);
      acc[1][0] = MFMA16(a1,b0,acc[1][0],0,0,0);
      acc[1][1] = MFMA16(a1,b1,acc[1][1],0,0,0);
    }
    __syncthreads();
  }
}

__device__ __forceinline__ void store_tile(void* C, int ldc, int m0, int n0, int M, int N,
    const float* bias, int relu, int bf16out, f32x4 (&acc)[2][2], int tid)
{
  const int lane = tid & 63, w = tid >> 6;
  const int wr = (w >> 1)*32, wc = (w & 1)*32;
  const int l15 = lane & 15, lg = lane >> 4;
  #pragma unroll
  for (int i = 0; i < 2; i++){
    #pragma unroll
    for (int j = 0; j < 2; j++){
      int col = n0 + wc + j*16 + l15;
      if (col < N){
        float bv = bias ? bias[col] : 0.0f;
        #pragma unroll
        for (int r = 0; r < 4; r++){
          int row = m0 + wr + i*16 + lg*4 + r;
          if (row < M){
            float v = acc[i][j][r] + bv;
            if (relu) v = fmaxf(v, 0.0f);
            if (bf16out) ((u16*)C)[(size_t)row*ldc + col] = f2bf(v);
            else         ((float*)C)[(size_t)row*ldc + col] = v;
          }
        }
      }
    }
  }
}

// ===================== PHASE B: p-GEMM + h-GEMM =====================
__global__ __launch_bounds__(256) void k_phaseB(
    const u16* __restrict__ qln, const u16* __restrict__ wqb, u16* __restrict__ pbuf,
    const u16* __restrict__ qxb, const u16* __restrict__ w1b,
    const float* __restrict__ b1, u16* __restrict__ hbuf)
{
  __shared__ __align__(16) u16 lA[64][64], lB[64][64];
  f32x4 acc[2][2] = {};
  const int bid = blockIdx.x, tid = threadIdx.x;
  if (bid < 64){
    int m0 = (bid>>3)*64, n0 = (bid&7)*64;
    gemm_body(qln, wqb, 512,512,512, m0,n0, tid, lA, lB, acc);
    store_tile(pbuf, 512, m0,n0, 512,512, nullptr, 0, 1, acc, tid);
  } else {
    int b = bid-64, m0 = (b>>5)*64, n0 = (b&31)*64;
    gemm_body(qxb, w1b, 512,2048,512, m0,n0, tid, lA, lB, acc);
    store_tile(hbuf, 2048, m0,n0, 512,2048, b1, 1, 1, acc, tid);
  }
}

// ============ PHASE C: pw-GEMM (fused m2/t2 epilogue) + x1-GEMM ============
__global__ __launch_bounds__(256) void k_phaseC(
    const u16* __restrict__ pbuf, const u16* __restrict__ wkt,
    const float* __restrict__ g_k, u16* __restrict__ m2, float* __restrict__ t2s,
    const u16* __restrict__ hbuf, const u16* __restrict__ w2b,
    const float* __restrict__ b2, float* __restrict__ x1o)
{
  __shared__ __align__(16) u16 lA[64][64], lB[64][64];
  f32x4 acc[2][2] = {};
  const int bid = blockIdx.x, tid = threadIdx.x;
  const int lane = tid & 63, w = tid >> 6;
  const int wr = (w >> 1)*32, wc = (w & 1)*32;
  const int l15 = lane & 15, lg = lane >> 4;
  if (bid < 64){
    int m0 = (bid>>3)*64, n0 = (bid&7)*64;
    gemm_body(pbuf, wkt, 512,512,512, m0,n0, tid, lA, lB, acc);
    #pragma unroll
    for (int i = 0; i < 2; i++){
      #pragma unroll
      for (int r = 0; r < 4; r++){
        int row = m0 + wr + i*16 + lg*4 + r;
        float part = 0.f;
        #pragma unroll
        for (int j = 0; j < 2; j++){
          int col = n0 + wc + j*16 + l15;
          float e = SCALE_C * acc[i][j][r] * g_k[col];
          m2[(size_t)row*512 + col] = f2bf(e);
          part += e;
        }
        #pragma unroll
        for (int o = 1; o < 16; o <<= 1) part += __shfl_xor(part, o);
        if (l15 == 0) atomicAdd(&t2s[row], part);
      }
    }
  } else {
    int b = bid-64, m0 = (b>>4)*64, n0 = (b&15)*64;
    gemm_body(hbuf, w2b, 512,1000,2048, m0,n0, tid, lA, lB, acc);
    store_tile(x1o, 1000, m0,n0, 512,1000, b2, 0, 0, acc, tid);
  }
}

// ===================== PHASE D: fused attention -> x2 =====================
// grid 1024, XCD-chunked swizzle. 512 thr. KX double-buffered in LDS via
// global_load_lds (2x16KB, P aliases); m2/qhat fragments reg-double-buffered
// from global (L2-hot). Counted vmcnt(10), raw barriers. (512,4): VGPR cap 128.
__global__ __launch_bounds__(512, 4) void k_attn(
    const u16* __restrict__ kxb, const u16* __restrict__ Gm,
    const u16* __restrict__ m2g, const u16* __restrict__ qhg,
    const float* __restrict__ km, const float* __restrict__ kr,
    const float* __restrict__ t2s, const void* __restrict__ maskp,
    const int* __restrict__ flagp, const float* __restrict__ lsp,
    float* __restrict__ x2)
{
  __shared__ __align__(16) u16 sb[16384];      // 32KB: 2 x KX[128][64]; P aliases all
  __shared__ float lt2[128];
  __shared__ float lNum[128][2], lDen[128][2];
  u16* lP = sb;                                 // [128][128] after main loop

  const int bid = blockIdx.x;
  const int xcd = bid & 7, j = bid >> 3;
  const int kb = xcd*32 + (j >> 2), q0 = (j & 3) * 128;
  const int tid = threadIdx.x, lane = tid & 63, w = tid >> 6;
  const int wr = (w >> 1)*32, wcol = (w & 1)*64;
  const int l15 = lane & 15, lg = lane >> 4;
  const int fl = *flagp;
  const float expls = __expf(lsp[0]);

  if (tid < 128) lt2[tid] = t2s[q0 + tid];

  float kmv[4], krv[4], mbv[4];
  #pragma unroll
  for (int jj = 0; jj < 4; jj++){
    int gn = kb*128 + wcol + jj*16 + l15;
    kmv[jj] = km[gn]; krv[jj] = kr[gn];
    int mv = fl ? ((const int*)maskp)[gn] : (int)((const unsigned char*)maskp)[gn];
    mbv[jj] = mv ? -1e30f : 0.0f;
  }

  const u16* KX = kxb + (size_t)kb * 65536;
  f32x4 aS[2][4] = {}, aD[2][4] = {};
  bf16x8s amr[2][2][2], aqr[2][2][2];   // [buf][kk][rowpair] — static idx via unroll

  // --- helpers (compile-time h under full unroll) ---
  #define STAGE_KX(cc) do{                                            \
    u16* base = sb + ((cc) & 1) * 8192;                               \
    _Pragma("unroll")                                                 \
    for (int i = 0; i < 2; i++){                                      \
      int row = w*16 + i*8 + (lane>>3);                               \
      int cgs = ((lane&7) ^ (row&7))*8;                               \
      gload16(KX + (size_t)row*512 + (cc)*64 + cgs, base + (w*16+i*8)*64); \
    } }while(0)

  #define LOAD_AQ(hb, cc) do{                                         \
    _Pragma("unroll")                                                 \
    for (int kk = 0; kk < 2; kk++){                                   \
      _Pragma("unroll")                                               \
      for (int rp = 0; rp < 2; rp++){                                 \
        size_t go = (size_t)(q0 + wr + rp*16 + l15)*512 + (cc)*64 + kk*32 + lg*8; \
        amr[hb][kk][rp] = *(const bf16x8s*)(m2g + go);                \
        aqr[hb][kk][rp] = *(const bf16x8s*)(qhg + go);                \
      } } }while(0)

  STAGE_KX(0);
  LOAD_AQ(0, 0);

  #pragma unroll
  for (int c = 0; c < 8; c++){
    const int h = c & 1;
    if (c < 7){
      STAGE_KX(c+1);
      LOAD_AQ((c+1)&1, c+1);
      asm volatile("s_waitcnt vmcnt(10)" ::: "memory");
    } else {
      asm volatile("s_waitcnt vmcnt(0)" ::: "memory");
    }
    __builtin_amdgcn_s_barrier();
    __builtin_amdgcn_sched_barrier(0);
    const u16* lKX = sb + h*8192;
    __builtin_amdgcn_s_setprio(1);
    #pragma unroll
    for (int kk = 0; kk < 2; kk++){
      #pragma unroll
      for (int jj = 0; jj < 4; jj++){
        int rB = wcol + jj*16 + l15;
        bf16x8s bk = *(const bf16x8s*)&lKX[rB*64 + (((kk*4+lg) ^ (rB&7))*8)];
        aS[0][jj] = MFMA16(amr[h][kk][0], bk, aS[0][jj], 0,0,0);
        aS[1][jj] = MFMA16(amr[h][kk][1], bk, aS[1][jj], 0,0,0);
        aD[0][jj] = MFMA16(aqr[h][kk][0], bk, aD[0][jj], 0,0,0);
        aD[1][jj] = MFMA16(aqr[h][kk][1], bk, aD[1][jj], 0,0,0);
      }
    }
    __builtin_amdgcn_s_setprio(0);
    __builtin_amdgcn_sched_barrier(0);
    __builtin_amdgcn_s_barrier();
  }
  __syncthreads();   // full drain (incl. lt2 ds_write) before P aliases sb

  // softmax (Z cancels in x2: raw E=exp(L)) + numer partials + P write
  #pragma unroll
  for (int i = 0; i < 2; i++){
    #pragma unroll
    for (int r = 0; r < 4; r++){
      int rowl = wr + i*16 + lg*4 + r;
      float t2v = lt2[rowl];
      float sn = 0.f;
      #pragma unroll
      for (int jj = 0; jj < 4; jj++){
        float L = krv[jj]*(aS[i][jj][r] - kmv[jj]*t2v) + mbv[jj];
        float e = __expf(L);
        aS[i][jj][r] = e;
        sn += e * aD[i][jj][r];
      }
      #pragma unroll
      for (int o = 1; o < 16; o <<= 1) sn += __shfl_xor(sn, o);
      if (l15 == 0) lNum[rowl][w&1] = sn;
      #pragma unroll
      for (int jj = 0; jj < 4; jj++){
        int n = wcol + jj*16 + l15;
        lP[rowl*128 + ((n>>3)^(rowl&7))*8 + (n&7)] = f2bf(aS[i][jj][r]);
      }
    }
  }
  __syncthreads();

  // T = E @ G (G symmetric: row-major B-frags straight from global, L2-hot)
  f32x4 aT[2][4] = {};
  const u16* Gk = Gm + (size_t)kb * 16384;
  #pragma unroll
  for (int kk = 0; kk < 4; kk++){
    int cgr = kk*4 + lg;
    int rA0 = wr + l15, rA1 = wr + 16 + l15;
    bf16x8s p0 = *(const bf16x8s*)&lP[rA0*128 + ((cgr^(rA0&7))*8)];
    bf16x8s p1 = *(const bf16x8s*)&lP[rA1*128 + ((cgr^(rA1&7))*8)];
    #pragma unroll
    for (int jj = 0; jj < 4; jj++){
      int mcol = wcol + jj*16 + l15;
      bf16x8s bg = *(const bf16x8s*)(Gk + (size_t)mcol*128 + kk*32 + lg*8);
      aT[0][jj] = MFMA16(p0, bg, aT[0][jj], 0,0,0);
      aT[1][jj] = MFMA16(p1, bg, aT[1][jj], 0,0,0);
    }
  }
  // denom^2 partials
  #pragma unroll
  for (int i = 0; i < 2; i++){
    #pragma unroll
    for (int r = 0; r < 4; r++){
      int rowl = wr + i*16 + lg*4 + r;
      float sd = 0.f;
      #pragma unroll
      for (int jj = 0; jj < 4; jj++) sd += aT[i][jj][r] * aS[i][jj][r];
      #pragma unroll
      for (int o = 1; o < 16; o <<= 1) sd += __shfl_xor(sd, o);
      if (l15 == 0) lDen[rowl][w&1] = sd;
    }
  }
  __syncthreads();

  if (tid < 128){
    float num  = lNum[tid][0] + lNum[tid][1];
    float den2 = lDen[tid][0] + lDen[tid][1];
    float den  = fmaxf(sqrtf(fmaxf(den2, 0.0f)), 1e-12f);
    x2[(size_t)(q0 + tid)*256 + kb] = expls * num / den;
  }
}

// ---------------------------------------------------------------------------
extern "C" void kernel_launch(void* const* d_in, const int* in_sizes, int n_in,
                              void* d_out, int out_size, void* d_ws, size_t ws_size,
                              hipStream_t stream)
{
  (void)in_sizes; (void)n_in; (void)out_size; (void)ws_size;
  const float* qx  = (const float*)d_in[0];
  const float* kx  = (const float*)d_in[1];
  const void*  mask= d_in[2];
  const float* lsp = (const float*)d_in[3];
  const float* g_q = (const float*)d_in[4];
  const float* b_q = (const float*)d_in[5];
  const float* g_k = (const float*)d_in[6];
  // d_in[7] (b_k): softmax-invariant per-q constant, dropped
  const float* wq  = (const float*)d_in[8];
  const float* wk  = (const float*)d_in[9];
  const float* w1  = (const float*)d_in[10];
  const float* b1  = (const float*)d_in[11];
  const float* w2  = (const float*)d_in[12];
  const float* b2  = (const float*)d_in[13];

  char* ws = (char*)d_ws;
  u16* kxb  = (u16*)(ws + OFF_KXB);
  u16* Gm   = (u16*)(ws + OFF_G);
  u16* w2b  = (u16*)(ws + OFF_W2B);
  u16* hbuf = (u16*)(ws + OFF_H);
  u16* w1b  = (u16*)(ws + OFF_W1B);
  u16* qln  = (u16*)(ws + OFF_QLN);
  u16* qhat = (u16*)(ws + OFF_QHAT);
  u16* qxb  = (u16*)(ws + OFF_QXB);
  u16* pbuf = (u16*)(ws + OFF_P);
  u16* m2   = (u16*)(ws + OFF_M2);
  u16* wqb  = (u16*)(ws + OFF_WQB);
  u16* wkt  = (u16*)(ws + OFF_WKT);
  float* km  = (float*)(ws + OFF_KM);
  float* kr  = (float*)(ws + OFF_KR);
  float* t2s = (float*)(ws + OFF_T2);
  int*   flag= (int*)(ws + OFF_FLAG);
  float* x1o = (float*)d_out;
  float* x2o = (float*)d_out + 512*1000;

  k_gram_fused<<<dim3(256), dim3(512), 0, stream>>>(kx, kxb, km, kr, Gm);
  k_phaseA<<<dim3(4049), dim3(256), 0, stream>>>(
      qx, (const int*)mask, g_q, b_q, wq, wk, w1, w2,
      qln, qhat, qxb, wqb, wkt, w1b, w2b, t2s, flag);
  k_phaseB<<<dim3(320), dim3(256), 0, stream>>>(
      qln, wqb, pbuf, qxb, w1b, b1, hbuf);
  k_phaseC<<<dim3(192), dim3(256), 0, stream>>>(
      pbuf, wkt, g_k, m2, t2s, hbuf, w2b, b2, x1o);
  k_attn<<<dim3(1024), dim3(512), 0, stream>>>(
      kxb, Gm, m2, qhat, km, kr, t2s, mask, flag, lsp, x2o);
}

// Round 7
// 160.763 us; speedup vs baseline: 1.3691x; 1.3691x over previous
//
#include <hip/hip_runtime.h>

typedef unsigned short u16;
typedef unsigned int u32;
typedef short bf16x8s __attribute__((ext_vector_type(8)));
typedef float f32x4 __attribute__((ext_vector_type(4)));

#define SCALE_C 0.044194173824159216f  // 512^-0.5
#define MFMA16 __builtin_amdgcn_mfma_f32_16x16x32_bf16

__device__ __forceinline__ u16 f2bf(float f){
  union { float f; u32 u; } c; c.f = f;
  u32 u = c.u;
  return (u16)((u + 0x7fffu + ((u >> 16) & 1u)) >> 16);
}

__device__ __forceinline__ void gload16(const void* g, void* l){
  __builtin_amdgcn_global_load_lds((const __attribute__((address_space(1))) void*)g,
                                   (__attribute__((address_space(3))) void*)l, 16, 0, 0);
}

// ---------------- workspace layout (bytes) ----------------
#define OFF_KXB  ((size_t)0)                  // 32768*512*2
#define OFF_G    (OFF_KXB + 33554432)         // 256*128*128*2
#define OFF_W2B  (OFF_G + 8388608)            // 1000*2048*2
#define OFF_H    (OFF_W2B + 4096000)          // 512*2048*2
#define OFF_W1B  (OFF_H + 2097152)            // 2048*512*2
#define OFF_QLN  (OFF_W1B + 2097152)          // 512*512*2 each below
#define OFF_QHAT (OFF_QLN + 524288)
#define OFF_QXB  (OFF_QHAT + 524288)
#define OFF_P    (OFF_QXB + 524288)           // unused (kept for layout stability)
#define OFF_M2   (OFF_P + 524288)
#define OFF_WQB  (OFF_M2 + 524288)            // unused
#define OFF_WCT  (OFF_WQB + 524288)           // WcT[512][512] bf16
#define OFF_KM   (OFF_WCT + 524288)           // 32768*4
#define OFF_KR   (OFF_KM + 131072)
#define OFF_T2   (OFF_KR + 131072)            // 512*4
#define OFF_FLAG (OFF_T2 + 4096)

// ======== GRAM32: prep_k + G with 32KB LDS (BK=128, 4 chunks) =============
// Per kb: interleave {read f32 chunk, stats-accum, bf16->global+LDS, MFMA G}.
__global__ __launch_bounds__(512) void k_gram32(
    const float* __restrict__ kx, u16* __restrict__ kxb,
    float* __restrict__ km, float* __restrict__ kr, u16* __restrict__ Gm)
{
  __shared__ __align__(16) u16 lk[128*128];   // 32 KB, XOR-swizzled
  const int z = blockIdx.x, tid = threadIdx.x;
  const int lane = tid & 63, w = tid >> 6;    // 8 waves
  const int l15 = lane & 15, lg = lane >> 4;
  const int a0 = (w>>2)*64, b0 = (w&3)*32;    // G wave-tile [64][32]
  float s[16] = {0,0,0,0,0,0,0,0,0,0,0,0,0,0,0,0};
  float sq[16] = {0,0,0,0,0,0,0,0,0,0,0,0,0,0,0,0};
  f32x4 acc[4][2] = {};
  for (int ch = 0; ch < 4; ch++){
    // wave w owns rows [w*16, w*16+16); lane covers cols ch*128 + lane*2
    #pragma unroll
    for (int i = 0; i < 16; i++){
      int r = w*16 + i;
      float2 v = *(const float2*)(kx + ((size_t)z*128 + r)*512 + ch*128 + lane*2);
      s[i] += v.x + v.y; sq[i] += v.x*v.x + v.y*v.y;
      u32 pk = f2bf(v.x) | ((u32)f2bf(v.y)<<16);
      *(u32*)(kxb + ((size_t)z*128 + r)*512 + ch*128 + lane*2) = pk;
      *(u32*)&lk[r*128 + ((lane*2) ^ ((r&7)<<3))] = pk;
    }
    __syncthreads();
    #pragma unroll
    for (int kk = 0; kk < 4; kk++){
      int cgr = kk*4 + lg;   // 8-u16 group 0..15
      bf16x8s a[4], b[2];
      #pragma unroll
      for (int i2 = 0; i2 < 4; i2++){
        int r = a0 + i2*16 + l15;
        a[i2] = *(const bf16x8s*)&lk[r*128 + ((cgr*8) ^ ((r&7)<<3))];
      }
      #pragma unroll
      for (int j = 0; j < 2; j++){
        int r = b0 + j*16 + l15;
        b[j] = *(const bf16x8s*)&lk[r*128 + ((cgr*8) ^ ((r&7)<<3))];
      }
      #pragma unroll
      for (int i2 = 0; i2 < 4; i2++)
        #pragma unroll
        for (int j = 0; j < 2; j++)
          acc[i2][j] = MFMA16(a[i2], b[j], acc[i2][j], 0,0,0);
    }
    __syncthreads();
  }
  #pragma unroll
  for (int i = 0; i < 16; i++){
    float ss = s[i], qq = sq[i];
    #pragma unroll
    for (int o = 1; o < 64; o <<= 1){ ss += __shfl_xor(ss,o); qq += __shfl_xor(qq,o); }
    if (lane == 0){
      int r = w*16 + i;
      float mean = ss*(1.0f/512.0f);
      float var  = qq*(1.0f/512.0f) - mean*mean;
      km[z*128+r] = mean; kr[z*128+r] = rsqrtf(var + 1e-5f);
    }
  }
  u16* G = Gm + (size_t)z*16384;
  #pragma unroll
  for (int i2 = 0; i2 < 4; i2++)
    #pragma unroll
    for (int j = 0; j < 2; j++)
      #pragma unroll
      for (int r = 0; r < 4; r++)
        G[(size_t)(a0 + i2*16 + lg*4 + r)*128 + b0 + j*16 + l15] = f2bf(acc[i2][j][r]);
}

// ========== PHASE A: prep_q, w1/w2 cvt, WcT = wk^T-contract-wq, mask =======
// [0,512) prep_q | [512,1536) w1 | [1536,3536) w2 | [3536,3600) WcT | 3600 mask
__global__ __launch_bounds__(256) void k_phaseA(
    const float* __restrict__ qx, const int* __restrict__ maskw,
    const float* __restrict__ g_q, const float* __restrict__ b_q,
    const float* __restrict__ wq, const float* __restrict__ wk,
    const float* __restrict__ w1, const float* __restrict__ w2,
    u16* __restrict__ qln, u16* __restrict__ qhat, u16* __restrict__ qxb,
    u16* __restrict__ wct, u16* __restrict__ w1b, u16* __restrict__ w2b,
    float* __restrict__ t2s, int* __restrict__ flag)
{
  __shared__ __align__(16) u16 shA[4096];   // 8 KB  (Wc A-tile)
  __shared__ __align__(16) u16 shB[4096];   // 8 KB  (Wc B-tile)
  __shared__ float redq[4][2];
  __shared__ int smax;
  const int bid = blockIdx.x, tid = threadIdx.x;
  if (bid < 512){
    const int row = bid;
    const int lane = tid & 63, wv = tid >> 6;
    float2 v = *(const float2*)(qx + (size_t)row*512 + tid*2);
    float s = v.x+v.y, sq = v.x*v.x+v.y*v.y;
    #pragma unroll
    for (int o = 1; o < 64; o <<= 1){ s += __shfl_xor(s,o); sq += __shfl_xor(sq,o); }
    if (lane == 0){ redq[wv][0]=s; redq[wv][1]=sq; }
    __syncthreads();
    s  = redq[0][0]+redq[1][0]+redq[2][0]+redq[3][0];
    sq = redq[0][1]+redq[1][1]+redq[2][1]+redq[3][1];
    float mean = s*(1.0f/512.0f);
    float var  = sq*(1.0f/512.0f) - mean*mean;
    float rstd = rsqrtf(var + 1e-5f);
    float il2  = 1.0f / fmaxf(sqrtf(sq), 1e-12f);
    float2 g  = *(const float2*)(g_q + tid*2);
    float2 bb = *(const float2*)(b_q + tid*2);
    u32 a  = f2bf((v.x-mean)*rstd*g.x+bb.x) | ((u32)f2bf((v.y-mean)*rstd*g.y+bb.y)<<16);
    u32 h  = f2bf(v.x*il2) | ((u32)f2bf(v.y*il2)<<16);
    u32 xx = f2bf(v.x)     | ((u32)f2bf(v.y)<<16);
    *(u32*)(qln  + (size_t)row*512 + tid*2) = a;
    *(u32*)(qhat + (size_t)row*512 + tid*2) = h;
    *(u32*)(qxb  + (size_t)row*512 + tid*2) = xx;
  } else if (bid < 3536){
    const float* in; u16* out; int i;
    if (bid < 1536) { in = w1; out = w1b; i = (bid-512)*256 + tid; }
    else            { in = w2; out = w2b; i = (bid-1536)*256 + tid; }
    float4 v = *(const float4*)(in + (size_t)i*4);
    uint2 p;
    p.x = f2bf(v.x)|((u32)f2bf(v.y)<<16); p.y = f2bf(v.z)|((u32)f2bf(v.w)<<16);
    *(uint2*)(out + (size_t)i*4) = p;
  } else if (bid < 3600){
    // WcT[f][c] = sum_i wk[i][f] * wq[i][c]  (pw = qln @ Wc reads rows f, contig c)
    const int t = bid - 3536;
    const int f0 = (t>>3)*64, c0 = (t&7)*64;
    const int lane = tid & 63, w = tid >> 6;
    const int wr = (w >> 1)*32, wc = (w & 1)*32;
    const int l15 = lane & 15, lg = lane >> 4;
    f32x4 acc[2][2] = {};
    for (int i0 = 0; i0 < 512; i0 += 64){
      const int ii = tid >> 2;            // 0..63 (i-local)
      #pragma unroll
      for (int e4 = 0; e4 < 4; e4++){
        int cc = (tid&3)*16 + e4*4;       // 0..60
        float4 va = *(const float4*)(wk + (size_t)(i0+ii)*512 + f0 + cc);
        float4 vb = *(const float4*)(wq + (size_t)(i0+ii)*512 + c0 + cc);
        #pragma unroll
        for (int e = 0; e < 4; e++){
          int rowc = cc + e;
          int idx = rowc*64 + (((ii>>3) ^ (rowc&7))*8 + (ii&7));
          shA[idx] = f2bf((&va.x)[e]);
          shB[idx] = f2bf((&vb.x)[e]);
        }
      }
      __syncthreads();
      #pragma unroll
      for (int kk = 0; kk < 2; kk++){
        int cgr = kk*4 + lg;
        int ra0 = wr + l15, ra1 = wr + 16 + l15;
        int rb0 = wc + l15, rb1 = wc + 16 + l15;
        bf16x8s a0 = *(const bf16x8s*)&shA[ra0*64 + ((cgr ^ (ra0&7))*8)];
        bf16x8s a1 = *(const bf16x8s*)&shA[ra1*64 + ((cgr ^ (ra1&7))*8)];
        bf16x8s b0 = *(const bf16x8s*)&shB[rb0*64 + ((cgr ^ (rb0&7))*8)];
        bf16x8s b1 = *(const bf16x8s*)&shB[rb1*64 + ((cgr ^ (rb1&7))*8)];
        acc[0][0]=MFMA16(a0,b0,acc[0][0],0,0,0);
        acc[0][1]=MFMA16(a0,b1,acc[0][1],0,0,0);
        acc[1][0]=MFMA16(a1,b0,acc[1][0],0,0,0);
        acc[1][1]=MFMA16(a1,b1,acc[1][1],0,0,0);
      }
      __syncthreads();
    }
    #pragma unroll
    for (int i = 0; i < 2; i++)
      #pragma unroll
      for (int j = 0; j < 2; j++)
        #pragma unroll
        for (int r = 0; r < 4; r++)
          wct[(size_t)(f0 + wr + i*16 + lg*4 + r)*512 + c0 + wc + j*16 + l15]
              = f2bf(acc[i][j][r]);
  } else {
    if (tid == 0) smax = 0;
    t2s[tid] = 0.0f; t2s[tid+256] = 0.0f;
    __syncthreads();
    int mx = 0;
    for (int i = tid; i < 8192; i += 256){ int v = maskw[i]; mx = v > mx ? v : mx; }
    #pragma unroll
    for (int o = 1; o < 64; o <<= 1){ int t2 = __shfl_xor(mx,o); mx = t2 > mx ? t2 : mx; }
    if ((tid & 63) == 0) atomicMax(&smax, mx);
    __syncthreads();
    if (tid == 0) *flag = (smax <= 1) ? 1 : 0;
  }
}

// ------------- 64x64 GEMM body (proven, register-staged) ---------
__device__ __forceinline__ void gemm_body(const u16* __restrict__ Ap, const u16* __restrict__ Bp,
    int M, int N, int K, int m0, int n0, int tid,
    u16 (*lA)[64], u16 (*lB)[64], f32x4 (&acc)[2][2])
{
  const int lane = tid & 63, w = tid >> 6;
  const int wr = (w >> 1)*32, wc = (w & 1)*32;
  const int l15 = lane & 15, lg = lane >> 4;
  for (int kc = 0; kc < K; kc += 64){
    #pragma unroll
    for (int s = 0; s < 2; s++){
      int u = tid + s*256;
      int row = u >> 3, cg = u & 7;
      int sw = (cg ^ (row & 7)) * 8;
      uint4 va = make_uint4(0,0,0,0);
      if (m0 + row < M) va = *(const uint4*)(Ap + (size_t)(m0+row)*K + kc + cg*8);
      *(uint4*)&lA[row][sw] = va;
      uint4 vb = make_uint4(0,0,0,0);
      if (n0 + row < N) vb = *(const uint4*)(Bp + (size_t)(n0+row)*K + kc + cg*8);
      *(uint4*)&lB[row][sw] = vb;
    }
    __syncthreads();
    #pragma unroll
    for (int kk = 0; kk < 2; kk++){
      int cgr = kk*4 + lg;
      int ra0 = wr + l15, ra1 = wr + 16 + l15;
      int rb0 = wc + l15, rb1 = wc + 16 + l15;
      bf16x8s a0 = *(const bf16x8s*)&lA[ra0][(cgr ^ (ra0&7))*8];
      bf16x8s a1 = *(const bf16x8s*)&lA[ra1][(cgr ^ (ra1&7))*8];
      bf16x8s b0 = *(const bf16x8s*)&lB[rb0][(cgr ^ (rb0&7))*8];
      bf16x8s b1 = *(const bf16x8s*)&lB[rb1][(cgr ^ (rb1&7))*8];
      acc[0][0] = MFMA16(a0,b0,acc[0][0],0,0,0);
      acc[0][1] = MFMA16(a0,b1,acc[0][1],0,0,0);
      acc[1][0] = MFMA16(a1,b0,acc[1][0],0,0,0);
      acc[1][1] = MFMA16(a1,b1,acc[1][1],0,0,0);
    }
    __syncthreads();
  }
}

__device__ __forceinline__ void store_tile(void* C, int ldc, int m0, int n0, int M, int N,
    const float* bias, int relu, int bf16out, f32x4 (&acc)[2][2], int tid)
{
  const int lane = tid & 63, w = tid >> 6;
  const int wr = (w >> 1)*32, wc = (w & 1)*32;
  const int l15 = lane & 15, lg = lane >> 4;
  #pragma unroll
  for (int i = 0; i < 2; i++){
    #pragma unroll
    for (int j = 0; j < 2; j++){
      int col = n0 + wc + j*16 + l15;
      if (col < N){
        float bv = bias ? bias[col] : 0.0f;
        #pragma unroll
        for (int r = 0; r < 4; r++){
          int row = m0 + wr + i*16 + lg*4 + r;
          if (row < M){
            float v = acc[i][j][r] + bv;
            if (relu) v = fmaxf(v, 0.0f);
            if (bf16out) ((u16*)C)[(size_t)row*ldc + col] = f2bf(v);
            else         ((float*)C)[(size_t)row*ldc + col] = v;
          }
        }
      }
    }
  }
}

// ===== PHASE B: pw = qln@WcT (+m2/t2 epilogue) and h = relu(qx@w1^T+b1) ====
__global__ __launch_bounds__(256) void k_phaseB(
    const u16* __restrict__ qln, const u16* __restrict__ wct,
    const float* __restrict__ g_k, u16* __restrict__ m2, float* __restrict__ t2s,
    const u16* __restrict__ qxb, const u16* __restrict__ w1b,
    const float* __restrict__ b1, u16* __restrict__ hbuf)
{
  __shared__ __align__(16) u16 lA[64][64], lB[64][64];
  f32x4 acc[2][2] = {};
  const int bid = blockIdx.x, tid = threadIdx.x;
  const int lane = tid & 63, w = tid >> 6;
  const int wr = (w >> 1)*32, wc = (w & 1)*32;
  const int l15 = lane & 15, lg = lane >> 4;
  if (bid < 64){
    int m0 = (bid>>3)*64, n0 = (bid&7)*64;
    gemm_body(qln, wct, 512,512,512, m0,n0, tid, lA, lB, acc);
    #pragma unroll
    for (int i = 0; i < 2; i++){
      #pragma unroll
      for (int r = 0; r < 4; r++){
        int row = m0 + wr + i*16 + lg*4 + r;
        float part = 0.f;
        #pragma unroll
        for (int j = 0; j < 2; j++){
          int col = n0 + wc + j*16 + l15;
          float e = SCALE_C * acc[i][j][r] * g_k[col];
          m2[(size_t)row*512 + col] = f2bf(e);
          part += e;
        }
        #pragma unroll
        for (int o = 1; o < 16; o <<= 1) part += __shfl_xor(part, o);
        if (l15 == 0) atomicAdd(&t2s[row], part);
      }
    }
  } else {
    int b = bid-64, m0 = (b>>5)*64, n0 = (b&31)*64;
    gemm_body(qxb, w1b, 512,2048,512, m0,n0, tid, lA, lB, acc);
    store_tile(hbuf, 2048, m0,n0, 512,2048, b1, 1, 1, acc, tid);
  }
}

// ============ PHASE D: fused attention -> x2, plus x1-GEMM blocks ==========
// blockIdx.x < 256: attn (round-5 proven body, 61-64us).
// blockIdx.x >= 256: x1 = h@w2^T+b2 (512-thr 64x128-tile GEMM).
__global__ __launch_bounds__(512, 4) void k_attn(
    const u16* __restrict__ kxb, const u16* __restrict__ Gm,
    const u16* __restrict__ m2, const u16* __restrict__ qhat,
    const float* __restrict__ km, const float* __restrict__ kr,
    const float* __restrict__ t2s, const void* __restrict__ maskp,
    const int* __restrict__ flagp, const float* __restrict__ lsp,
    float* __restrict__ x2,
    const u16* __restrict__ hbuf, const u16* __restrict__ w2b,
    const float* __restrict__ b2, float* __restrict__ x1o)
{
  __shared__ __align__(16) u16 lBig[3*8192];   // 48KB
  __shared__ float lt2[128];
  __shared__ float lNum[128][2], lDen[128][2];

  const int tid = threadIdx.x, lane = tid & 63, w = tid >> 6;
  const int l15 = lane & 15, lg = lane >> 4;

  if (blockIdx.x >= 256){
    // -------- x1 GEMM: tile [64 m][128 n], 8 waves (2 row x 4 col) --------
    const int t = (blockIdx.x - 256)*4 + blockIdx.y;   // 0..63
    const int m0 = (t>>3)*64, n0 = (t&7)*128;
    const int wr = (w >> 2)*32, wc = (w & 3)*32;
    u16* lA = lBig;           // [64][64]
    u16* lB = lBig + 4096;    // [128][64]
    f32x4 acc[2][2] = {};
    for (int kc = 0; kc < 2048; kc += 64){
      {
        int row = tid >> 3, cg = tid & 7;
        *(uint4*)&lA[row*64 + ((cg ^ (row&7))*8)] =
            *(const uint4*)(hbuf + (size_t)(m0+row)*2048 + kc + cg*8);
        #pragma unroll
        for (int s2 = 0; s2 < 2; s2++){
          int u = tid + s2*512;
          int rowb = u >> 3, cgb = u & 7;
          uint4 vb = make_uint4(0,0,0,0);
          if (n0 + rowb < 1000)
            vb = *(const uint4*)(w2b + (size_t)(n0+rowb)*2048 + kc + cgb*8);
          *(uint4*)&lB[rowb*64 + ((cgb ^ (rowb&7))*8)] = vb;
        }
      }
      __syncthreads();
      #pragma unroll
      for (int kk = 0; kk < 2; kk++){
        int cgr = kk*4 + lg;
        int ra0 = wr + l15, ra1 = wr + 16 + l15;
        int rb0 = wc + l15, rb1 = wc + 16 + l15;
        bf16x8s a0 = *(const bf16x8s*)&lA[ra0*64 + ((cgr ^ (ra0&7))*8)];
        bf16x8s a1 = *(const bf16x8s*)&lA[ra1*64 + ((cgr ^ (ra1&7))*8)];
        bf16x8s b0 = *(const bf16x8s*)&lB[rb0*64 + ((cgr ^ (rb0&7))*8)];
        bf16x8s b1 = *(const bf16x8s*)&lB[rb1*64 + ((cgr ^ (rb1&7))*8)];
        acc[0][0]=MFMA16(a0,b0,acc[0][0],0,0,0);
        acc[0][1]=MFMA16(a0,b1,acc[0][1],0,0,0);
        acc[1][0]=MFMA16(a1,b0,acc[1][0],0,0,0);
        acc[1][1]=MFMA16(a1,b1,acc[1][1],0,0,0);
      }
      __syncthreads();
    }
    #pragma unroll
    for (int i = 0; i < 2; i++){
      #pragma unroll
      for (int j = 0; j < 2; j++){
        int col = n0 + wc + j*16 + l15;
        if (col < 1000){
          float bv = b2[col];
          #pragma unroll
          for (int r = 0; r < 4; r++){
            int row = m0 + wr + i*16 + lg*4 + r;
            x1o[(size_t)row*1000 + col] = acc[i][j][r] + bv;
          }
        }
      }
    }
    return;
  }

  // ----------------------- attn (round-5 proven) -----------------------
  u16* lKX = lBig;           // [128][64] swizzled
  u16* lM2 = lBig + 8192;
  u16* lQH = lBig + 16384;
  u16* lP  = lBig;           // [128][128] (after main loop; KX+M2 dead)

  const int kb = blockIdx.x, q0 = blockIdx.y * 128;
  const int wr = (w >> 1)*32, wcol = (w & 1)*64;
  const int fl = *flagp;
  const float expls = __expf(lsp[0]);

  if (tid < 128) lt2[tid] = t2s[q0 + tid];

  float kmv[4], krv[4], mbv[4];
  #pragma unroll
  for (int j = 0; j < 4; j++){
    int gn = kb*128 + wcol + j*16 + l15;
    kmv[j] = km[gn]; krv[j] = kr[gn];
    int mv = fl ? ((const int*)maskp)[gn] : (int)((const unsigned char*)maskp)[gn];
    mbv[j] = mv ? -1e30f : 0.0f;
  }

  const u16* KX = kxb + (size_t)kb * 65536;
  f32x4 aS[2][4] = {}, aD[2][4] = {};

  for (int kc = 0; kc < 512; kc += 64){
    #pragma unroll
    for (int i = 0; i < 2; i++){
      int row = w*16 + i*8 + (lane>>3);
      int cgs = ((lane&7) ^ (row&7))*8;
      int lo = (w*16 + i*8)*64;
      gload16(KX   + (size_t)row*512      + kc + cgs, lBig + lo);
      gload16(m2   + (size_t)(q0+row)*512 + kc + cgs, lBig + 8192 + lo);
      gload16(qhat + (size_t)(q0+row)*512 + kc + cgs, lBig + 16384 + lo);
    }
    __syncthreads();
    #pragma unroll
    for (int kk = 0; kk < 2; kk++){
      int cgr = kk*4 + lg;
      int rA0 = wr + l15, rA1 = wr + 16 + l15;
      bf16x8s am0 = *(const bf16x8s*)&lM2[rA0*64 + (cgr^(rA0&7))*8];
      bf16x8s am1 = *(const bf16x8s*)&lM2[rA1*64 + (cgr^(rA1&7))*8];
      bf16x8s aq0 = *(const bf16x8s*)&lQH[rA0*64 + (cgr^(rA0&7))*8];
      bf16x8s aq1 = *(const bf16x8s*)&lQH[rA1*64 + (cgr^(rA1&7))*8];
      #pragma unroll
      for (int j = 0; j < 4; j++){
        int rB = wcol + j*16 + l15;
        bf16x8s bk = *(const bf16x8s*)&lKX[rB*64 + (cgr^(rB&7))*8];
        aS[0][j] = MFMA16(am0, bk, aS[0][j], 0,0,0);
        aS[1][j] = MFMA16(am1, bk, aS[1][j], 0,0,0);
        aD[0][j] = MFMA16(aq0, bk, aD[0][j], 0,0,0);
        aD[1][j] = MFMA16(aq1, bk, aD[1][j], 0,0,0);
      }
    }
    __syncthreads();
  }

  // softmax (Z cancels in x2: raw E=exp(L)) + numer partials + P write
  #pragma unroll
  for (int i = 0; i < 2; i++){
    #pragma unroll
    for (int r = 0; r < 4; r++){
      int rowl = wr + i*16 + lg*4 + r;
      float t2v = lt2[rowl];
      float sn = 0.f;
      #pragma unroll
      for (int j = 0; j < 4; j++){
        float L = krv[j]*(aS[i][j][r] - kmv[j]*t2v) + mbv[j];
        float e = __expf(L);
        aS[i][j][r] = e;
        sn += e * aD[i][j][r];
      }
      #pragma unroll
      for (int o = 1; o < 16; o <<= 1) sn += __shfl_xor(sn, o);
      if (l15 == 0) lNum[rowl][w&1] = sn;
      #pragma unroll
      for (int j = 0; j < 4; j++){
        int n = wcol + j*16 + l15;
        lP[rowl*128 + ((n>>3)^(rowl&7))*8 + (n&7)] = f2bf(aS[i][j][r]);
      }
    }
  }
  __syncthreads();

  // T = E @ G (G symmetric: row-major B-frags straight from global, L2-hot)
  f32x4 aT[2][4] = {};
  const u16* Gk = Gm + (size_t)kb * 16384;
  #pragma unroll
  for (int kk = 0; kk < 4; kk++){
    int cgr = kk*4 + lg;
    int rA0 = wr + l15, rA1 = wr + 16 + l15;
    bf16x8s p0 = *(const bf16x8s*)&lP[rA0*128 + ((cgr^(rA0&7))*8)];
    bf16x8s p1 = *(const bf16x8s*)&lP[rA1*128 + ((cgr^(rA1&7))*8)];
    #pragma unroll
    for (int j = 0; j < 4; j++){
      int mcol = wcol + j*16 + l15;
      bf16x8s bg = *(const bf16x8s*)(Gk + (size_t)mcol*128 + kk*32 + lg*8);
      aT[0][j] = MFMA16(p0, bg, aT[0][j], 0,0,0);
      aT[1][j] = MFMA16(p1, bg, aT[1][j], 0,0,0);
    }
  }
  // denom^2 partials
  #pragma unroll
  for (int i = 0; i < 2; i++){
    #pragma unroll
    for (int r = 0; r < 4; r++){
      int rowl = wr + i*16 + lg*4 + r;
      float sd = 0.f;
      #pragma unroll
      for (int j = 0; j < 4; j++) sd += aT[i][j][r] * aS[i][j][r];
      #pragma unroll
      for (int o = 1; o < 16; o <<= 1) sd += __shfl_xor(sd, o);
      if (l15 == 0) lDen[rowl][w&1] = sd;
    }
  }
  __syncthreads();

  if (tid < 128){
    float num  = lNum[tid][0] + lNum[tid][1];
    float den2 = lDen[tid][0] + lDen[tid][1];
    float den  = fmaxf(sqrtf(fmaxf(den2, 0.0f)), 1e-12f);
    x2[(size_t)(q0 + tid)*256 + kb] = expls * num / den;
  }
}

// ---------------------------------------------------------------------------
extern "C" void kernel_launch(void* const* d_in, const int* in_sizes, int n_in,
                              void* d_out, int out_size, void* d_ws, size_t ws_size,
                              hipStream_t stream)
{
  (void)in_sizes; (void)n_in; (void)out_size; (void)ws_size;
  const float* qx  = (const float*)d_in[0];
  const float* kx  = (const float*)d_in[1];
  const void*  mask= d_in[2];
  const float* lsp = (const float*)d_in[3];
  const float* g_q = (const float*)d_in[4];
  const float* b_q = (const float*)d_in[5];
  const float* g_k = (const float*)d_in[6];
  // d_in[7] (b_k): softmax-invariant per-q constant, dropped
  const float* wq  = (const float*)d_in[8];
  const float* wk  = (const float*)d_in[9];
  const float* w1  = (const float*)d_in[10];
  const float* b1  = (const float*)d_in[11];
  const float* w2  = (const float*)d_in[12];
  const float* b2  = (const float*)d_in[13];

  char* ws = (char*)d_ws;
  u16* kxb  = (u16*)(ws + OFF_KXB);
  u16* Gm   = (u16*)(ws + OFF_G);
  u16* w2b  = (u16*)(ws + OFF_W2B);
  u16* hbuf = (u16*)(ws + OFF_H);
  u16* w1b  = (u16*)(ws + OFF_W1B);
  u16* qln  = (u16*)(ws + OFF_QLN);
  u16* qhat = (u16*)(ws + OFF_QHAT);
  u16* qxb  = (u16*)(ws + OFF_QXB);
  u16* m2   = (u16*)(ws + OFF_M2);
  u16* wct  = (u16*)(ws + OFF_WCT);
  float* km  = (float*)(ws + OFF_KM);
  float* kr  = (float*)(ws + OFF_KR);
  float* t2s = (float*)(ws + OFF_T2);
  int*   flag= (int*)(ws + OFF_FLAG);
  float* x1o = (float*)d_out;
  float* x2o = (float*)d_out + 512*1000;

  k_gram32<<<dim3(256), dim3(512), 0, stream>>>(kx, kxb, km, kr, Gm);
  k_phaseA<<<dim3(3601), dim3(256), 0, stream>>>(
      qx, (const int*)mask, g_q, b_q, wq, wk, w1, w2,
      qln, qhat, qxb, wct, w1b, w2b, t2s, flag);
  k_phaseB<<<dim3(320), dim3(256), 0, stream>>>(
      qln, wct, g_k, m2, t2s, qxb, w1b, b1, hbuf);
  k_attn<<<dim3(272, 4), dim3(512), 0, stream>>>(
      kxb, Gm, m2, qhat, km, kr, t2s, mask, flag, lsp, x2o,
      hbuf, w2b, b2, x1o);
}

// Round 8
// 149.211 us; speedup vs baseline: 1.4751x; 1.0774x over previous
//
#include <hip/hip_runtime.h>

typedef unsigned short u16;
typedef unsigned int u32;
typedef short bf16x8s __attribute__((ext_vector_type(8)));
typedef float f32x4 __attribute__((ext_vector_type(4)));

#define SCALE_C 0.044194173824159216f  // 512^-0.5
#define MFMA16 __builtin_amdgcn_mfma_f32_16x16x32_bf16

__device__ __forceinline__ u16 f2bf(float f){
  union { float f; u32 u; } c; c.f = f;
  u32 u = c.u;
  return (u16)((u + 0x7fffu + ((u >> 16) & 1u)) >> 16);
}

__device__ __forceinline__ void gload16(const void* g, void* l){
  __builtin_amdgcn_global_load_lds((const __attribute__((address_space(1))) void*)g,
                                   (__attribute__((address_space(3))) void*)l, 16, 0, 0);
}

// ---------------- workspace layout (bytes) ----------------
#define OFF_KXB  ((size_t)0)                  // 32768*512*2
#define OFF_G    (OFF_KXB + 33554432)         // 256*128*128*2
#define OFF_W2B  (OFF_G + 8388608)            // 1000*2048*2
#define OFF_H    (OFF_W2B + 4096000)          // 512*2048*2
#define OFF_W1B  (OFF_H + 2097152)            // 2048*512*2
#define OFF_QLN  (OFF_W1B + 2097152)          // 512*512*2 each below
#define OFF_QHAT (OFF_QLN + 524288)
#define OFF_QXB  (OFF_QHAT + 524288)
#define OFF_P    (OFF_QXB + 524288)           // unused (layout stability)
#define OFF_M2   (OFF_P + 524288)
#define OFF_WQB  (OFF_M2 + 524288)            // unused
#define OFF_WCT  (OFF_WQB + 524288)           // WcT[512][512] bf16
#define OFF_KM   (OFF_WCT + 524288)           // 32768*4
#define OFF_KR   (OFF_KM + 131072)
#define OFF_T2   (OFF_KR + 131072)            // 512*4
#define OFF_FLAG (OFF_T2 + 4096)

// ======== GRAM32: prep_k + G with 32KB LDS (BK=128, 4 chunks) =============
__global__ __launch_bounds__(512) void k_gram32(
    const float* __restrict__ kx, u16* __restrict__ kxb,
    float* __restrict__ km, float* __restrict__ kr, u16* __restrict__ Gm)
{
  __shared__ __align__(16) u16 lk[128*128];   // 32 KB, XOR-swizzled
  const int z = blockIdx.x, tid = threadIdx.x;
  const int lane = tid & 63, w = tid >> 6;    // 8 waves
  const int l15 = lane & 15, lg = lane >> 4;
  const int a0 = (w>>2)*64, b0 = (w&3)*32;    // G wave-tile [64][32]
  float s[16] = {0,0,0,0,0,0,0,0,0,0,0,0,0,0,0,0};
  float sq[16] = {0,0,0,0,0,0,0,0,0,0,0,0,0,0,0,0};
  f32x4 acc[4][2] = {};
  for (int ch = 0; ch < 4; ch++){
    #pragma unroll
    for (int i = 0; i < 16; i++){
      int r = w*16 + i;
      float2 v = *(const float2*)(kx + ((size_t)z*128 + r)*512 + ch*128 + lane*2);
      s[i] += v.x + v.y; sq[i] += v.x*v.x + v.y*v.y;
      u32 pk = f2bf(v.x) | ((u32)f2bf(v.y)<<16);
      *(u32*)(kxb + ((size_t)z*128 + r)*512 + ch*128 + lane*2) = pk;
      *(u32*)&lk[r*128 + ((lane*2) ^ ((r&7)<<3))] = pk;
    }
    __syncthreads();
    #pragma unroll
    for (int kk = 0; kk < 4; kk++){
      int cgr = kk*4 + lg;
      bf16x8s a[4], b[2];
      #pragma unroll
      for (int i2 = 0; i2 < 4; i2++){
        int r = a0 + i2*16 + l15;
        a[i2] = *(const bf16x8s*)&lk[r*128 + ((cgr*8) ^ ((r&7)<<3))];
      }
      #pragma unroll
      for (int j = 0; j < 2; j++){
        int r = b0 + j*16 + l15;
        b[j] = *(const bf16x8s*)&lk[r*128 + ((cgr*8) ^ ((r&7)<<3))];
      }
      #pragma unroll
      for (int i2 = 0; i2 < 4; i2++)
        #pragma unroll
        for (int j = 0; j < 2; j++)
          acc[i2][j] = MFMA16(a[i2], b[j], acc[i2][j], 0,0,0);
    }
    __syncthreads();
  }
  #pragma unroll
  for (int i = 0; i < 16; i++){
    float ss = s[i], qq = sq[i];
    #pragma unroll
    for (int o = 1; o < 64; o <<= 1){ ss += __shfl_xor(ss,o); qq += __shfl_xor(qq,o); }
    if (lane == 0){
      int r = w*16 + i;
      float mean = ss*(1.0f/512.0f);
      float var  = qq*(1.0f/512.0f) - mean*mean;
      km[z*128+r] = mean; kr[z*128+r] = rsqrtf(var + 1e-5f);
    }
  }
  u16* G = Gm + (size_t)z*16384;
  #pragma unroll
  for (int i2 = 0; i2 < 4; i2++)
    #pragma unroll
    for (int j = 0; j < 2; j++)
      #pragma unroll
      for (int r = 0; r < 4; r++)
        G[(size_t)(a0 + i2*16 + lg*4 + r)*128 + b0 + j*16 + l15] = f2bf(acc[i2][j][r]);
}

// ========== PHASE A: prep_q, w1/w2 cvt, WcT = wk^T-contract-wq, mask =======
__global__ __launch_bounds__(256) void k_phaseA(
    const float* __restrict__ qx, const int* __restrict__ maskw,
    const float* __restrict__ g_q, const float* __restrict__ b_q,
    const float* __restrict__ wq, const float* __restrict__ wk,
    const float* __restrict__ w1, const float* __restrict__ w2,
    u16* __restrict__ qln, u16* __restrict__ qhat, u16* __restrict__ qxb,
    u16* __restrict__ wct, u16* __restrict__ w1b, u16* __restrict__ w2b,
    float* __restrict__ t2s, int* __restrict__ flag)
{
  __shared__ __align__(16) u16 shA[4096];
  __shared__ __align__(16) u16 shB[4096];
  __shared__ float redq[4][2];
  __shared__ int smax;
  const int bid = blockIdx.x, tid = threadIdx.x;
  if (bid < 512){
    const int row = bid;
    const int lane = tid & 63, wv = tid >> 6;
    float2 v = *(const float2*)(qx + (size_t)row*512 + tid*2);
    float s = v.x+v.y, sq = v.x*v.x+v.y*v.y;
    #pragma unroll
    for (int o = 1; o < 64; o <<= 1){ s += __shfl_xor(s,o); sq += __shfl_xor(sq,o); }
    if (lane == 0){ redq[wv][0]=s; redq[wv][1]=sq; }
    __syncthreads();
    s  = redq[0][0]+redq[1][0]+redq[2][0]+redq[3][0];
    sq = redq[0][1]+redq[1][1]+redq[2][1]+redq[3][1];
    float mean = s*(1.0f/512.0f);
    float var  = sq*(1.0f/512.0f) - mean*mean;
    float rstd = rsqrtf(var + 1e-5f);
    float il2  = 1.0f / fmaxf(sqrtf(sq), 1e-12f);
    float2 g  = *(const float2*)(g_q + tid*2);
    float2 bb = *(const float2*)(b_q + tid*2);
    u32 a  = f2bf((v.x-mean)*rstd*g.x+bb.x) | ((u32)f2bf((v.y-mean)*rstd*g.y+bb.y)<<16);
    u32 h  = f2bf(v.x*il2) | ((u32)f2bf(v.y*il2)<<16);
    u32 xx = f2bf(v.x)     | ((u32)f2bf(v.y)<<16);
    *(u32*)(qln  + (size_t)row*512 + tid*2) = a;
    *(u32*)(qhat + (size_t)row*512 + tid*2) = h;
    *(u32*)(qxb  + (size_t)row*512 + tid*2) = xx;
  } else if (bid < 3536){
    const float* in; u16* out; int i;
    if (bid < 1536) { in = w1; out = w1b; i = (bid-512)*256 + tid; }
    else            { in = w2; out = w2b; i = (bid-1536)*256 + tid; }
    float4 v = *(const float4*)(in + (size_t)i*4);
    uint2 p;
    p.x = f2bf(v.x)|((u32)f2bf(v.y)<<16); p.y = f2bf(v.z)|((u32)f2bf(v.w)<<16);
    *(uint2*)(out + (size_t)i*4) = p;
  } else if (bid < 3600){
    // WcT[f][c] = sum_i wk[i][f] * wq[i][c]
    const int t = bid - 3536;
    const int f0 = (t>>3)*64, c0 = (t&7)*64;
    const int lane = tid & 63, w = tid >> 6;
    const int wr = (w >> 1)*32, wc = (w & 1)*32;
    const int l15 = lane & 15, lg = lane >> 4;
    f32x4 acc[2][2] = {};
    for (int i0 = 0; i0 < 512; i0 += 64){
      const int ii = tid >> 2;
      #pragma unroll
      for (int e4 = 0; e4 < 4; e4++){
        int cc = (tid&3)*16 + e4*4;
        float4 va = *(const float4*)(wk + (size_t)(i0+ii)*512 + f0 + cc);
        float4 vb = *(const float4*)(wq + (size_t)(i0+ii)*512 + c0 + cc);
        #pragma unroll
        for (int e = 0; e < 4; e++){
          int rowc = cc + e;
          int idx = rowc*64 + (((ii>>3) ^ (rowc&7))*8 + (ii&7));
          shA[idx] = f2bf((&va.x)[e]);
          shB[idx] = f2bf((&vb.x)[e]);
        }
      }
      __syncthreads();
      #pragma unroll
      for (int kk = 0; kk < 2; kk++){
        int cgr = kk*4 + lg;
        int ra0 = wr + l15, ra1 = wr + 16 + l15;
        int rb0 = wc + l15, rb1 = wc + 16 + l15;
        bf16x8s a0 = *(const bf16x8s*)&shA[ra0*64 + ((cgr ^ (ra0&7))*8)];
        bf16x8s a1 = *(const bf16x8s*)&shA[ra1*64 + ((cgr ^ (ra1&7))*8)];
        bf16x8s b0 = *(const bf16x8s*)&shB[rb0*64 + ((cgr ^ (rb0&7))*8)];
        bf16x8s b1 = *(const bf16x8s*)&shB[rb1*64 + ((cgr ^ (rb1&7))*8)];
        acc[0][0]=MFMA16(a0,b0,acc[0][0],0,0,0);
        acc[0][1]=MFMA16(a0,b1,acc[0][1],0,0,0);
        acc[1][0]=MFMA16(a1,b0,acc[1][0],0,0,0);
        acc[1][1]=MFMA16(a1,b1,acc[1][1],0,0,0);
      }
      __syncthreads();
    }
    #pragma unroll
    for (int i = 0; i < 2; i++)
      #pragma unroll
      for (int j = 0; j < 2; j++)
        #pragma unroll
        for (int r = 0; r < 4; r++)
          wct[(size_t)(f0 + wr + i*16 + lg*4 + r)*512 + c0 + wc + j*16 + l15]
              = f2bf(acc[i][j][r]);
  } else {
    if (tid == 0) smax = 0;
    t2s[tid] = 0.0f; t2s[tid+256] = 0.0f;
    __syncthreads();
    int mx = 0;
    for (int i = tid; i < 8192; i += 256){ int v = maskw[i]; mx = v > mx ? v : mx; }
    #pragma unroll
    for (int o = 1; o < 64; o <<= 1){ int t2 = __shfl_xor(mx,o); mx = t2 > mx ? t2 : mx; }
    if ((tid & 63) == 0) atomicMax(&smax, mx);
    __syncthreads();
    if (tid == 0) *flag = (smax <= 1) ? 1 : 0;
  }
}

// ------------- 64x64 GEMM body (proven, register-staged) ---------
__device__ __forceinline__ void gemm_body(const u16* __restrict__ Ap, const u16* __restrict__ Bp,
    int M, int N, int K, int m0, int n0, int tid,
    u16 (*lA)[64], u16 (*lB)[64], f32x4 (&acc)[2][2])
{
  const int lane = tid & 63, w = tid >> 6;
  const int wr = (w >> 1)*32, wc = (w & 1)*32;
  const int l15 = lane & 15, lg = lane >> 4;
  for (int kc = 0; kc < K; kc += 64){
    #pragma unroll
    for (int s = 0; s < 2; s++){
      int u = tid + s*256;
      int row = u >> 3, cg = u & 7;
      int sw = (cg ^ (row & 7)) * 8;
      uint4 va = make_uint4(0,0,0,0);
      if (m0 + row < M) va = *(const uint4*)(Ap + (size_t)(m0+row)*K + kc + cg*8);
      *(uint4*)&lA[row][sw] = va;
      uint4 vb = make_uint4(0,0,0,0);
      if (n0 + row < N) vb = *(const uint4*)(Bp + (size_t)(n0+row)*K + kc + cg*8);
      *(uint4*)&lB[row][sw] = vb;
    }
    __syncthreads();
    #pragma unroll
    for (int kk = 0; kk < 2; kk++){
      int cgr = kk*4 + lg;
      int ra0 = wr + l15, ra1 = wr + 16 + l15;
      int rb0 = wc + l15, rb1 = wc + 16 + l15;
      bf16x8s a0 = *(const bf16x8s*)&lA[ra0][(cgr ^ (ra0&7))*8];
      bf16x8s a1 = *(const bf16x8s*)&lA[ra1][(cgr ^ (ra1&7))*8];
      bf16x8s b0 = *(const bf16x8s*)&lB[rb0][(cgr ^ (rb0&7))*8];
      bf16x8s b1 = *(const bf16x8s*)&lB[rb1][(cgr ^ (rb1&7))*8];
      acc[0][0] = MFMA16(a0,b0,acc[0][0],0,0,0);
      acc[0][1] = MFMA16(a0,b1,acc[0][1],0,0,0);
      acc[1][0] = MFMA16(a1,b0,acc[1][0],0,0,0);
      acc[1][1] = MFMA16(a1,b1,acc[1][1],0,0,0);
    }
    __syncthreads();
  }
}

__device__ __forceinline__ void store_tile(void* C, int ldc, int m0, int n0, int M, int N,
    const float* bias, int relu, int bf16out, f32x4 (&acc)[2][2], int tid)
{
  const int lane = tid & 63, w = tid >> 6;
  const int wr = (w >> 1)*32, wc = (w & 1)*32;
  const int l15 = lane & 15, lg = lane >> 4;
  #pragma unroll
  for (int i = 0; i < 2; i++){
    #pragma unroll
    for (int j = 0; j < 2; j++){
      int col = n0 + wc + j*16 + l15;
      if (col < N){
        float bv = bias ? bias[col] : 0.0f;
        #pragma unroll
        for (int r = 0; r < 4; r++){
          int row = m0 + wr + i*16 + lg*4 + r;
          if (row < M){
            float v = acc[i][j][r] + bv;
            if (relu) v = fmaxf(v, 0.0f);
            if (bf16out) ((u16*)C)[(size_t)row*ldc + col] = f2bf(v);
            else         ((float*)C)[(size_t)row*ldc + col] = v;
          }
        }
      }
    }
  }
}

// ===== PHASE B: pw = qln@WcT (+m2/t2 epilogue) and h = relu(qx@w1^T+b1) ====
__global__ __launch_bounds__(256) void k_phaseB(
    const u16* __restrict__ qln, const u16* __restrict__ wct,
    const float* __restrict__ g_k, u16* __restrict__ m2, float* __restrict__ t2s,
    const u16* __restrict__ qxb, const u16* __restrict__ w1b,
    const float* __restrict__ b1, u16* __restrict__ hbuf)
{
  __shared__ __align__(16) u16 lA[64][64], lB[64][64];
  f32x4 acc[2][2] = {};
  const int bid = blockIdx.x, tid = threadIdx.x;
  const int lane = tid & 63, w = tid >> 6;
  const int wr = (w >> 1)*32, wc = (w & 1)*32;
  const int l15 = lane & 15, lg = lane >> 4;
  if (bid < 64){
    int m0 = (bid>>3)*64, n0 = (bid&7)*64;
    gemm_body(qln, wct, 512,512,512, m0,n0, tid, lA, lB, acc);
    #pragma unroll
    for (int i = 0; i < 2; i++){
      #pragma unroll
      for (int r = 0; r < 4; r++){
        int row = m0 + wr + i*16 + lg*4 + r;
        float part = 0.f;
        #pragma unroll
        for (int j = 0; j < 2; j++){
          int col = n0 + wc + j*16 + l15;
          float e = SCALE_C * acc[i][j][r] * g_k[col];
          m2[(size_t)row*512 + col] = f2bf(e);
          part += e;
        }
        #pragma unroll
        for (int o = 1; o < 16; o <<= 1) part += __shfl_xor(part, o);
        if (l15 == 0) atomicAdd(&t2s[row], part);
      }
    }
  } else {
    int b = bid-64, m0 = (b>>5)*64, n0 = (b&31)*64;
    gemm_body(qxb, w1b, 512,2048,512, m0,n0, tid, lA, lB, acc);
    store_tile(hbuf, 2048, m0,n0, 512,2048, b1, 1, 1, acc, tid);
  }
}

// ============ PHASE D: x1-GEMM blocks FIRST, then attn -> x2 ===============
// blockIdx.x < 16: x1 = h@w2^T+b2 (dispatched first => no serial tail).
// blockIdx.x >= 16: attn, kb = blockIdx.x - 16 (round-5 proven body).
__global__ __launch_bounds__(512, 4) void k_attn(
    const u16* __restrict__ kxb, const u16* __restrict__ Gm,
    const u16* __restrict__ m2, const u16* __restrict__ qhat,
    const float* __restrict__ km, const float* __restrict__ kr,
    const float* __restrict__ t2s, const void* __restrict__ maskp,
    const int* __restrict__ flagp, const float* __restrict__ lsp,
    float* __restrict__ x2,
    const u16* __restrict__ hbuf, const u16* __restrict__ w2b,
    const float* __restrict__ b2, float* __restrict__ x1o)
{
  __shared__ __align__(16) u16 lBig[3*8192];   // 48KB
  __shared__ float lt2[128];
  __shared__ float lNum[128][2], lDen[128][2];

  const int tid = threadIdx.x, lane = tid & 63, w = tid >> 6;
  const int l15 = lane & 15, lg = lane >> 4;

  if (blockIdx.x < 16){
    // -------- x1 GEMM: tile [64 m][128 n], 8 waves (2 row x 4 col) --------
    const int t = blockIdx.x*4 + blockIdx.y;   // 0..63
    const int m0 = (t>>3)*64, n0 = (t&7)*128;
    const int wr = (w >> 2)*32, wc = (w & 3)*32;
    u16* lA = lBig;           // [64][64]
    u16* lB = lBig + 4096;    // [128][64]
    f32x4 acc[2][2] = {};
    for (int kc = 0; kc < 2048; kc += 64){
      {
        int row = tid >> 3, cg = tid & 7;
        *(uint4*)&lA[row*64 + ((cg ^ (row&7))*8)] =
            *(const uint4*)(hbuf + (size_t)(m0+row)*2048 + kc + cg*8);
        #pragma unroll
        for (int s2 = 0; s2 < 2; s2++){
          int u = tid + s2*512;
          int rowb = u >> 3, cgb = u & 7;
          uint4 vb = make_uint4(0,0,0,0);
          if (n0 + rowb < 1000)
            vb = *(const uint4*)(w2b + (size_t)(n0+rowb)*2048 + kc + cgb*8);
          *(uint4*)&lB[rowb*64 + ((cgb ^ (rowb&7))*8)] = vb;
        }
      }
      __syncthreads();
      #pragma unroll
      for (int kk = 0; kk < 2; kk++){
        int cgr = kk*4 + lg;
        int ra0 = wr + l15, ra1 = wr + 16 + l15;
        int rb0 = wc + l15, rb1 = wc + 16 + l15;
        bf16x8s a0 = *(const bf16x8s*)&lA[ra0*64 + ((cgr ^ (ra0&7))*8)];
        bf16x8s a1 = *(const bf16x8s*)&lA[ra1*64 + ((cgr ^ (ra1&7))*8)];
        bf16x8s b0 = *(const bf16x8s*)&lB[rb0*64 + ((cgr ^ (rb0&7))*8)];
        bf16x8s b1 = *(const bf16x8s*)&lB[rb1*64 + ((cgr ^ (rb1&7))*8)];
        acc[0][0]=MFMA16(a0,b0,acc[0][0],0,0,0);
        acc[0][1]=MFMA16(a0,b1,acc[0][1],0,0,0);
        acc[1][0]=MFMA16(a1,b0,acc[1][0],0,0,0);
        acc[1][1]=MFMA16(a1,b1,acc[1][1],0,0,0);
      }
      __syncthreads();
    }
    #pragma unroll
    for (int i = 0; i < 2; i++){
      #pragma unroll
      for (int j = 0; j < 2; j++){
        int col = n0 + wc + j*16 + l15;
        if (col < 1000){
          float bv = b2[col];
          #pragma unroll
          for (int r = 0; r < 4; r++){
            int row = m0 + wr + i*16 + lg*4 + r;
            x1o[(size_t)row*1000 + col] = acc[i][j][r] + bv;
          }
        }
      }
    }
    return;
  }

  // ----------------------- attn (round-5 proven) -----------------------
  u16* lKX = lBig;           // [128][64] swizzled
  u16* lM2 = lBig + 8192;
  u16* lQH = lBig + 16384;
  u16* lP  = lBig;           // [128][128] (after main loop; KX+M2 dead)

  const int kb = blockIdx.x - 16, q0 = blockIdx.y * 128;
  const int wr = (w >> 1)*32, wcol = (w & 1)*64;
  const int fl = *flagp;
  const float expls = __expf(lsp[0]);

  if (tid < 128) lt2[tid] = t2s[q0 + tid];

  float kmv[4], krv[4], mbv[4];
  #pragma unroll
  for (int j = 0; j < 4; j++){
    int gn = kb*128 + wcol + j*16 + l15;
    kmv[j] = km[gn]; krv[j] = kr[gn];
    int mv = fl ? ((const int*)maskp)[gn] : (int)((const unsigned char*)maskp)[gn];
    mbv[j] = mv ? -1e30f : 0.0f;
  }

  const u16* KX = kxb + (size_t)kb * 65536;
  f32x4 aS[2][4] = {}, aD[2][4] = {};

  for (int kc = 0; kc < 512; kc += 64){
    #pragma unroll
    for (int i = 0; i < 2; i++){
      int row = w*16 + i*8 + (lane>>3);
      int cgs = ((lane&7) ^ (row&7))*8;
      int lo = (w*16 + i*8)*64;
      gload16(KX   + (size_t)row*512      + kc + cgs, lBig + lo);
      gload16(m2   + (size_t)(q0+row)*512 + kc + cgs, lBig + 8192 + lo);
      gload16(qhat + (size_t)(q0+row)*512 + kc + cgs, lBig + 16384 + lo);
    }
    __syncthreads();
    #pragma unroll
    for (int kk = 0; kk < 2; kk++){
      int cgr = kk*4 + lg;
      int rA0 = wr + l15, rA1 = wr + 16 + l15;
      bf16x8s am0 = *(const bf16x8s*)&lM2[rA0*64 + (cgr^(rA0&7))*8];
      bf16x8s am1 = *(const bf16x8s*)&lM2[rA1*64 + (cgr^(rA1&7))*8];
      bf16x8s aq0 = *(const bf16x8s*)&lQH[rA0*64 + (cgr^(rA0&7))*8];
      bf16x8s aq1 = *(const bf16x8s*)&lQH[rA1*64 + (cgr^(rA1&7))*8];
      #pragma unroll
      for (int j = 0; j < 4; j++){
        int rB = wcol + j*16 + l15;
        bf16x8s bk = *(const bf16x8s*)&lKX[rB*64 + (cgr^(rB&7))*8];
        aS[0][j] = MFMA16(am0, bk, aS[0][j], 0,0,0);
        aS[1][j] = MFMA16(am1, bk, aS[1][j], 0,0,0);
        aD[0][j] = MFMA16(aq0, bk, aD[0][j], 0,0,0);
        aD[1][j] = MFMA16(aq1, bk, aD[1][j], 0,0,0);
      }
    }
    __syncthreads();
  }

  // softmax (Z cancels in x2: raw E=exp(L)) + numer partials + P write
  #pragma unroll
  for (int i = 0; i < 2; i++){
    #pragma unroll
    for (int r = 0; r < 4; r++){
      int rowl = wr + i*16 + lg*4 + r;
      float t2v = lt2[rowl];
      float sn = 0.f;
      #pragma unroll
      for (int j = 0; j < 4; j++){
        float L = krv[j]*(aS[i][j][r] - kmv[j]*t2v) + mbv[j];
        float e = __expf(L);
        aS[i][j][r] = e;
        sn += e * aD[i][j][r];
      }
      #pragma unroll
      for (int o = 1; o < 16; o <<= 1) sn += __shfl_xor(sn, o);
      if (l15 == 0) lNum[rowl][w&1] = sn;
      #pragma unroll
      for (int j = 0; j < 4; j++){
        int n = wcol + j*16 + l15;
        lP[rowl*128 + ((n>>3)^(rowl&7))*8 + (n&7)] = f2bf(aS[i][j][r]);
      }
    }
  }
  __syncthreads();

  // T = E @ G (G symmetric: row-major B-frags straight from global, L2-hot)
  f32x4 aT[2][4] = {};
  const u16* Gk = Gm + (size_t)kb * 16384;
  #pragma unroll
  for (int kk = 0; kk < 4; kk++){
    int cgr = kk*4 + lg;
    int rA0 = wr + l15, rA1 = wr + 16 + l15;
    bf16x8s p0 = *(const bf16x8s*)&lP[rA0*128 + ((cgr^(rA0&7))*8)];
    bf16x8s p1 = *(const bf16x8s*)&lP[rA1*128 + ((cgr^(rA1&7))*8)];
    #pragma unroll
    for (int j = 0; j < 4; j++){
      int mcol = wcol + j*16 + l15;
      bf16x8s bg = *(const bf16x8s*)(Gk + (size_t)mcol*128 + kk*32 + lg*8);
      aT[0][j] = MFMA16(p0, bg, aT[0][j], 0,0,0);
      aT[1][j] = MFMA16(p1, bg, aT[1][j], 0,0,0);
    }
  }
  // denom^2 partials
  #pragma unroll
  for (int i = 0; i < 2; i++){
    #pragma unroll
    for (int r = 0; r < 4; r++){
      int rowl = wr + i*16 + lg*4 + r;
      float sd = 0.f;
      #pragma unroll
      for (int j = 0; j < 4; j++) sd += aT[i][j][r] * aS[i][j][r];
      #pragma unroll
      for (int o = 1; o < 16; o <<= 1) sd += __shfl_xor(sd, o);
      if (l15 == 0) lDen[rowl][w&1] = sd;
    }
  }
  __syncthreads();

  if (tid < 128){
    float num  = lNum[tid][0] + lNum[tid][1];
    float den2 = lDen[tid][0] + lDen[tid][1];
    float den  = fmaxf(sqrtf(fmaxf(den2, 0.0f)), 1e-12f);
    x2[(size_t)(q0 + tid)*256 + kb] = expls * num / den;
  }
}

// ---------------------------------------------------------------------------
extern "C" void kernel_launch(void* const* d_in, const int* in_sizes, int n_in,
                              void* d_out, int out_size, void* d_ws, size_t ws_size,
                              hipStream_t stream)
{
  (void)in_sizes; (void)n_in; (void)out_size; (void)ws_size;
  const float* qx  = (const float*)d_in[0];
  const float* kx  = (const float*)d_in[1];
  const void*  mask= d_in[2];
  const float* lsp = (const float*)d_in[3];
  const float* g_q = (const float*)d_in[4];
  const float* b_q = (const float*)d_in[5];
  const float* g_k = (const float*)d_in[6];
  // d_in[7] (b_k): softmax-invariant per-q constant, dropped
  const float* wq  = (const float*)d_in[8];
  const float* wk  = (const float*)d_in[9];
  const float* w1  = (const float*)d_in[10];
  const float* b1  = (const float*)d_in[11];
  const float* w2  = (const float*)d_in[12];
  const float* b2  = (const float*)d_in[13];

  char* ws = (char*)d_ws;
  u16* kxb  = (u16*)(ws + OFF_KXB);
  u16* Gm   = (u16*)(ws + OFF_G);
  u16* w2b  = (u16*)(ws + OFF_W2B);
  u16* hbuf = (u16*)(ws + OFF_H);
  u16* w1b  = (u16*)(ws + OFF_W1B);
  u16* qln  = (u16*)(ws + OFF_QLN);
  u16* qhat = (u16*)(ws + OFF_QHAT);
  u16* qxb  = (u16*)(ws + OFF_QXB);
  u16* m2   = (u16*)(ws + OFF_M2);
  u16* wct  = (u16*)(ws + OFF_WCT);
  float* km  = (float*)(ws + OFF_KM);
  float* kr  = (float*)(ws + OFF_KR);
  float* t2s = (float*)(ws + OFF_T2);
  int*   flag= (int*)(ws + OFF_FLAG);
  float* x1o = (float*)d_out;
  float* x2o = (float*)d_out + 512*1000;

  k_gram32<<<dim3(256), dim3(512), 0, stream>>>(kx, kxb, km, kr, Gm);
  k_phaseA<<<dim3(3601), dim3(256), 0, stream>>>(
      qx, (const int*)mask, g_q, b_q, wq, wk, w1, w2,
      qln, qhat, qxb, wct, w1b, w2b, t2s, flag);
  k_phaseB<<<dim3(320), dim3(256), 0, stream>>>(
      qln, wct, g_k, m2, t2s, qxb, w1b, b1, hbuf);
  k_attn<<<dim3(272, 4), dim3(512), 0, stream>>>(
      kxb, Gm, m2, qhat, km, kr, t2s, mask, flag, lsp, x2o,
      hbuf, w2b, b2, x1o);
}